// Round 12
// baseline (177.347 us; speedup 1.0000x reference)
//
#include <hip/hip_runtime.h>
#include <math.h>
#include <stdint.h>

#define B_ROWS 2048
#define D_DIM  512
#define V_COLS 32000
#define BM 128
#define BN 128
#define BK 64
#define KSTEPS (D_DIM / BK)             // 8
#define NCT    (V_COLS / BN)            // 250 col tiles
#define TILE_B (BM * BK)                // 8192 B per A (or B) tile buffer
#define S_SC   30.0f
#define COS_M  0.8775825618903728f      // cos(0.5)
#define SIN_M  0.479425538604203f       // sin(0.5)

typedef float f32x4 __attribute__((ext_vector_type(4)));
typedef long  i64x2 __attribute__((ext_vector_type(2)));

__device__ __forceinline__ void load16_to_lds(const void* g, void* l) {
  __builtin_amdgcn_global_load_lds(
      (__attribute__((address_space(1))) void*)(g),
      (__attribute__((address_space(3))) void*)(l),
      16, 0, 0);
}

// ---------- kernel 1: fused row L2-normalize (x,W) fp32 -> fp8 e4m3, + zero rowsum/out ----------
__global__ void fused_norm_kernel(const float* __restrict__ x,
                                  const float* __restrict__ W,
                                  uint8_t* __restrict__ nx,
                                  uint8_t* __restrict__ nw,
                                  float* __restrict__ rowsum,
                                  float* __restrict__ out) {
  if (blockIdx.x == 0 && threadIdx.x == 0) out[0] = 0.f;
  if (blockIdx.x < B_ROWS / 256) rowsum[blockIdx.x * 256 + threadIdx.x] = 0.f;
  const int lane = threadIdx.x & 63;
  const int wave = threadIdx.x >> 6;
  const int gr   = blockIdx.x * 4 + wave;
  const float* src;
  uint8_t* dst;
  if (gr < B_ROWS) {
    src = x + (size_t)gr * D_DIM;
    dst = nx + (size_t)gr * D_DIM;
  } else {
    src = W + (size_t)(gr - B_ROWS) * D_DIM;
    dst = nw + (size_t)(gr - B_ROWS) * D_DIM;
  }
  const float4* r4 = (const float4*)src;
  float4 v0 = r4[2 * lane];
  float4 v1 = r4[2 * lane + 1];
  float ss = v0.x*v0.x + v0.y*v0.y + v0.z*v0.z + v0.w*v0.w
           + v1.x*v1.x + v1.y*v1.y + v1.z*v1.z + v1.w*v1.w;
  #pragma unroll
  for (int off = 32; off >= 1; off >>= 1) ss += __shfl_xor(ss, off, 64);
  float inv = 1.0f / fmaxf(sqrtf(ss), 1e-12f);
  int p0 = __builtin_amdgcn_cvt_pk_fp8_f32(v0.x * inv, v0.y * inv, 0, false);
  p0     = __builtin_amdgcn_cvt_pk_fp8_f32(v0.z * inv, v0.w * inv, p0, true);
  int p1 = __builtin_amdgcn_cvt_pk_fp8_f32(v1.x * inv, v1.y * inv, 0, false);
  p1     = __builtin_amdgcn_cvt_pk_fp8_f32(v1.z * inv, v1.w * inv, p1, true);
  ((int2*)dst)[lane] = make_int2(p0, p1);
}

// ---------- kernel 2: fp8 GEMM (nx @ nW^T), BK=64, RING-3 distance-2 pipeline ----------
// R11 K-loop body (proven: 87.5 us, 0 conflicts, FETCH 12 MB) with the sync structure
// replaced: 3 LDS buffers, prefetch issued 2 steps ahead, RAW s_barrier (no vmcnt
// drain) + per-wave s_waitcnt vmcnt(8) -> tiles k+1,k+2 stay in flight across both
// barriers and the compute phase. Hazards: stage(k+2) overwrites buf[(k-1)%3] whose
// readers passed the trailing barrier of step k-1; leading barrier preceded by every
// wave's vmcnt(8) makes tile k resident block-wide; trailing barrier carries
// lgkmcnt(0) (already satisfied by MFMA operand deps).
__global__ __launch_bounds__(256, 4)
void arc_gemm_kernel(const uint8_t* __restrict__ nx,
                     const uint8_t* __restrict__ nw,
                     const int* __restrict__ labels,
                     float* __restrict__ rowsum,
                     float* __restrict__ lbl_logit) {
  __shared__ uint8_t sMem[3][2 * TILE_B];   // 48 KB: [buf][A 0..8191 | B 8192..16383]

  const int id = blockIdx.x;
  const int ct = ((id >> 7) << 3) | (id & 7);
  if (ct >= NCT) return;
  const int rt = (id >> 3) & 15;
  const int m0 = rt * BM;
  const int n0 = ct * BN;

  const int tid  = threadIdx.x;
  const int wave = tid >> 6;
  const int lane = tid & 63;
  const int wm   = wave >> 1;
  const int wn   = wave & 1;
  const int quad = lane >> 4;
  const int l16  = lane & 15;

  // staging (R4/R11-proven): inst i covers rows i*64 + (tid>>2); slot tid&3 <- chunk jg
  const int srow = tid >> 2;
  const int jg   = (tid & 3) ^ ((srow >> 1) & 3);
  const uint8_t* gA = nx + (size_t)(m0 + srow) * D_DIM + jg * 16;
  const uint8_t* gB = nw + (size_t)(n0 + srow) * D_DIM + jg * 16;
  const int offA0 = wave * 1024;                 // wave-uniform LDS byte bases
  const int offA1 = 4096 + wave * 1024;
  const int offB0 = TILE_B + wave * 1024;
  const int offB1 = TILE_B + 4096 + wave * 1024;

  // frag reads (R11-proven zero-conflict math)
  const int cSlot = (quad ^ ((l16 >> 1) & 3)) << 4;
  const int aBase = (wm * 64 + l16) * BK + cSlot;          // + mi*16*BK
  const int bBase = TILE_B + (wn * 64 + l16) * BK + cSlot; // + ni*16*BK

  f32x4 acc[4][4];
  #pragma unroll
  for (int i = 0; i < 4; ++i)
    #pragma unroll
    for (int j = 0; j < 4; ++j) acc[i][j] = (f32x4){0.f, 0.f, 0.f, 0.f};

  // prologue: tiles 0,1 -> bufs 0,1
  #pragma unroll
  for (int t = 0; t < 2; ++t) {
    load16_to_lds(gA + t * BK,              &sMem[t][offA0]);
    load16_to_lds(gA + 64 * D_DIM + t * BK, &sMem[t][offA1]);
    load16_to_lds(gB + t * BK,              &sMem[t][offB0]);
    load16_to_lds(gB + 64 * D_DIM + t * BK, &sMem[t][offB1]);
  }

  #pragma unroll
  for (int ks = 0; ks < KSTEPS; ++ks) {
    if (ks + 2 < KSTEPS) {                     // stage tile ks+2 (distance 2)
      const int nb  = (ks + 2) % 3;
      const int off = (ks + 2) * BK;
      load16_to_lds(gA + off,              &sMem[nb][offA0]);
      load16_to_lds(gA + 64 * D_DIM + off, &sMem[nb][offA1]);
      load16_to_lds(gB + off,              &sMem[nb][offB0]);
      load16_to_lds(gB + 64 * D_DIM + off, &sMem[nb][offB1]);
      asm volatile("s_waitcnt vmcnt(8)" ::: "memory");   // tile ks retired; k+1,k+2 in flight
    } else if (ks + 1 < KSTEPS) {
      asm volatile("s_waitcnt vmcnt(4)" ::: "memory");   // tile ks retired; k+1 in flight
    } else {
      asm volatile("s_waitcnt vmcnt(0)" ::: "memory");   // last tile retired
    }
    asm volatile("s_barrier" ::: "memory");    // rendezvous: tile ks resident block-wide

    const uint8_t* bA = &sMem[ks % 3][0];
    i64x2 a2[4];
    #pragma unroll
    for (int mi = 0; mi < 4; ++mi)
      a2[mi] = *(const i64x2*)(bA + aBase + mi * 16 * BK);
    #pragma unroll
    for (int ni = 0; ni < 4; ++ni) {
      const i64x2 b2 = *(const i64x2*)(bA + bBase + ni * 16 * BK);
      #pragma unroll
      for (int mi = 0; mi < 4; ++mi) {
        acc[mi][ni] = __builtin_amdgcn_mfma_f32_16x16x32_fp8_fp8(a2[mi][0], b2[0], acc[mi][ni], 0, 0, 0);
        acc[mi][ni] = __builtin_amdgcn_mfma_f32_16x16x32_fp8_fp8(a2[mi][1], b2[1], acc[mi][ni], 0, 0, 0);
      }
    }
    // release: all reads of buf[ks%3] done before any wave stages tile ks+3 into it
    asm volatile("s_waitcnt lgkmcnt(0)\n\ts_barrier" ::: "memory");
  }

  // Epilogue (R11-proven). C/D layout: col = lane&15, row = quad*4 + reg.
  const int lblv = labels[m0 + wm * 64 + lane];
  #pragma unroll
  for (int mi = 0; mi < 4; ++mi) {
    #pragma unroll
    for (int r = 0; r < 4; ++r) {
      const int rw   = mi * 16 + quad * 4 + r;
      const int grow = m0 + wm * 64 + rw;
      const int lbl  = __shfl(lblv, rw, 64);
      float rsum = 0.f;
      #pragma unroll
      for (int ni = 0; ni < 4; ++ni) {
        float c = acc[mi][ni][r];
        const int gcol = n0 + wn * 64 + ni * 16 + l16;
        if (gcol == lbl) {
          float sy  = sqrtf(fminf(1.f, fmaxf(0.f, 1.f - c * c)));
          float phi = c * COS_M - sy * SIN_M;
          lbl_logit[grow] = S_SC * phi;       // exactly one lane grid-wide
          c = phi;
        }
        rsum += __expf(S_SC * c - 30.0f);     // fixed shift: logits in [-30,30]
      }
      #pragma unroll
      for (int off = 1; off < 16; off <<= 1)
        rsum += __shfl_xor(rsum, off, 64);
      if (l16 == 0) atomicAdd(&rowsum[grow], rsum);
    }
  }
}

// ---------- kernel 3: per-row loss + global mean ----------
__global__ void arc_finish_kernel(const float* __restrict__ rowsum,
                                  const float* __restrict__ lbl_logit,
                                  float* __restrict__ out) {
  const int row  = blockIdx.x * 256 + threadIdx.x;   // 8 blocks x 256
  const int lane = threadIdx.x & 63;
  const int wave = threadIdx.x >> 6;
  float v = (30.0f + logf(rowsum[row]) - lbl_logit[row]) * (1.0f / (float)B_ROWS);
  #pragma unroll
  for (int off = 32; off >= 1; off >>= 1) v += __shfl_xor(v, off, 64);
  __shared__ float wsum[4];
  if (lane == 0) wsum[wave] = v;
  __syncthreads();
  if (threadIdx.x == 0) atomicAdd(out, wsum[0] + wsum[1] + wsum[2] + wsum[3]);
}

// ---------- launch ----------
extern "C" void kernel_launch(void* const* d_in, const int* in_sizes, int n_in,
                              void* d_out, int out_size, void* d_ws, size_t ws_size,
                              hipStream_t stream) {
  const float* x      = (const float*)d_in[0];
  const float* W      = (const float*)d_in[1];
  const int*   labels = (const int*)d_in[2];
  float* out = (float*)d_out;

  char* ws = (char*)d_ws;
  uint8_t* nx = (uint8_t*)ws;                                       // 1 MB
  uint8_t* nw = (uint8_t*)(ws + (size_t)B_ROWS * D_DIM);            // 16.4 MB
  char* p = ws + (size_t)B_ROWS * D_DIM + (size_t)V_COLS * D_DIM;
  float* rowsum    = (float*)p;  p += (size_t)B_ROWS * 4;           // 8 KB
  float* lbl_logit = (float*)p;                                     // 8 KB

  hipLaunchKernelGGL(fused_norm_kernel, dim3((B_ROWS + V_COLS) / 4), dim3(256), 0, stream,
                     x, W, nx, nw, rowsum, out);
  hipLaunchKernelGGL(arc_gemm_kernel, dim3(32 * 16 * 8), dim3(256), 0, stream,
                     nx, nw, labels, rowsum, lbl_logit);
  hipLaunchKernelGGL(arc_finish_kernel, dim3(B_ROWS / 256), dim3(256), 0, stream,
                     rowsum, lbl_logit, out);
}